// Round 3
// baseline (162.071 us; speedup 1.0000x reference)
//
#include <hip/hip_runtime.h>
#include <math.h>

#define NB 32
#define DM 128
#define SL 2048
#define WIN 64
#define NT  (SL / 16)    // 128 j-tiles of 16
#define PADF 4           // front pad tiles (j in [-64,0))
#define PADB 6           // back pad tiles  (j in [SL, SL+96))
#define NTP (NT + PADF + PADB)   // 138 tiles per (n)
#define YST 132          // ylds row stride (floats)

typedef __attribute__((ext_vector_type(8))) short bf16x8;
typedef __attribute__((ext_vector_type(4))) float f32x4;

__device__ inline ushort bf16_rne(float f) {
    union { float f; unsigned u; } v; v.f = f;
    unsigned u = v.u;
    return (ushort)((u + 0x7FFFu + ((u >> 16) & 1u)) >> 16);
}
__device__ inline float bf16_to_f(ushort h) {
    union { unsigned u; float f; } v; v.u = ((unsigned)h) << 16;
    return v.f;
}

// ---------------------------------------------------------------------------
// ws layout:
//   sqh   : NB*SL*DM ushort   sigmoid(q) as unorm16 (abs err <= 7.6e-6)
//   ekTF  : NB*NTP*2048 bf16  exp(k) in 16-j x 128-d tiles [n][jt][d][jo],
//                             jt offset by PADF; pad tiles zeroed by qkv bx<10
//   ekvTF : same              exp(k)*v
//   WB    : 128*2560 bf16     banded weights, A-frag order per 16-i tile
//   Pk/Pkv: NB*32*DM fp32     per-block partial sums (reduced inside band_out)
//   Wh/Wl : 4*128*128 bf16    split W (Wq,Wk,Wv,Wo), B-frag order
// ---------------------------------------------------------------------------

// Setup: blocks 0..127 pack W (B-frag, split hi/lo); 128..383 build WB
// (2 blocks per 16-i tile for 2x parallelism on the scattered pos_bias reads).
__global__ __launch_bounds__(512) void setup_kernel(
    const float* __restrict__ Wq, const float* __restrict__ Wk,
    const float* __restrict__ Wv, const float* __restrict__ Wo,
    const float* __restrict__ pos_bias,
    ushort* __restrict__ Wh, ushort* __restrict__ Wl,
    ushort* __restrict__ WB)
{
    const int b = blockIdx.x;
    const int tid = threadIdx.x;
    if (b < 128) {
        // ---- pack Wq/Wk/Wv/Wo into B-frag order, split hi/lo bf16 ----
        const int id = b;                 // (mat*8+ct)*4+ks
        const int mat = id >> 5;
        const int ct = (id & 31) >> 2, ks = id & 3;
        const int lane = tid >> 3, j = tid & 7;
        const int k = ks * 32 + (lane >> 4) * 8 + j;
        const int col = ct * 16 + (lane & 15);
        const float* W = (mat == 0) ? Wq : ((mat == 1) ? Wk : ((mat == 2) ? Wv : Wo));
        float w = W[k * DM + col];
        ushort h = bf16_rne(w);
        Wh[(size_t)id * 512 + tid] = h;
        Wl[(size_t)id * 512 + tid] = bf16_rne(w - bf16_to_f(h));
    } else {
        // ---- banded weights in A-frag order per 16-i tile, 2 blocks/tile ----
        const int idx = b - 128;          // 0..255
        const int it = idx >> 1;          // 0..127
        const int half = idx & 1;
        const int i0 = it * 16;
        const int tend = half * 1280 + 1280;
        for (int t = half * 1280 + tid; t < tend; t += 512) {
            const int ks = t >> 9;
            const int lane = (t >> 3) & 63;
            const int jj = t & 7;
            const int m = lane & 15;
            const int k = ks * 32 + ((lane >> 4) << 3) + jj;
            const int i = i0 + m;
            const int j = i0 - 64 + k;
            const int rel = k - 64 - m;  // j - i
            float val = 0.f;
            if (rel > -WIN && rel < WIN && j >= 0 && j < SL)
                val = __expf(pos_bias[(size_t)i * SL + j]) - 1.f;
            WB[(size_t)it * 2560 + t] = bf16_rne(val);
        }
    }
}

// QKV projection via split-bf16 MFMA.
// Block = (n, 64 l's), 512 threads / 8 waves; wave w owns dt slice w (16 d's)
// for all 3 matrices. Blocks bx<10 also zero the pad tiles of ekTF/ekvTF.
// Epilogue stores per-block partial sums to Pk/Pkv (no cross-XCD atomics).
__global__ __launch_bounds__(512, 4) void qkv_kernel(
    const float* __restrict__ x,
    const ushort* __restrict__ Wh, const ushort* __restrict__ Wl,
    const float* __restrict__ bq, const float* __restrict__ bk,
    const float* __restrict__ bv,
    ushort* __restrict__ sqh, ushort* __restrict__ ekTF, ushort* __restrict__ ekvTF,
    float* __restrict__ Pk, float* __restrict__ Pkv)
{
    __shared__ ushort Ah[64 * 128];   // frag order: ((lt*4+ks)*64+lane)*8+j
    __shared__ ushort Al[64 * 128];
    const int n = blockIdx.y, bx = blockIdx.x, l0 = bx * 64;
    const int tid = threadIdx.x;
    const int wave = tid >> 6;        // = dt slice 0..7
    const int lane = tid & 63;

    // Pad-tile zeroing (front 4 + back 6 tiles per n), done by blocks bx<10.
    if (bx < 10) {
        const int jt_p = (bx < PADF) ? bx : (NT + bx);   // 0..3, 132..137
        const size_t zb = ((size_t)n * NTP + jt_p) * 2048 + (size_t)tid * 4;
        ushort4 z; z.x = 0; z.y = 0; z.z = 0; z.w = 0;
        *(ushort4*)&ekTF [zb] = z;
        *(ushort4*)&ekvTF[zb] = z;
    }

    const bf16x8* WhV = (const bf16x8*)Wh;
    const bf16x8* WlV = (const bf16x8*)Wl;

    // Prefetch ks=0 weight fragments before staging (hide L2 latency).
    bf16x8 bh0[3], bl0[3];
    #pragma unroll
    for (int m = 0; m < 3; ++m) {
        const int fi = ((m * 8 + wave) * 4 + 0) * 64 + lane;
        bh0[m] = WhV[fi];
        bl0[m] = WlV[fi];
    }

    {
        const int lo = lane;
        const int cq = wave;              // 0..7
        const int l  = l0 + lo;
        for (int cc = 0; cc < 4; ++cc) {
            const int c0 = cc * 32 + cq * 4;
            float xv[4]; ushort hh[4], ll[4];
            #pragma unroll
            for (int u = 0; u < 4; ++u)
                xv[u] = x[((size_t)n * DM + c0 + u) * SL + l];
            #pragma unroll
            for (int u = 0; u < 4; ++u) {
                hh[u] = bf16_rne(xv[u]);
                ll[u] = bf16_rne(xv[u] - bf16_to_f(hh[u]));
            }
            const int idx = ((lo >> 4) * 4 + (c0 >> 5)) * 512
                          + (((c0 >> 3) & 3) * 16 + (lo & 15)) * 8 + (c0 & 7);
            ushort4 hv; hv.x = hh[0]; hv.y = hh[1]; hv.z = hh[2]; hv.w = hh[3];
            ushort4 lv; lv.x = ll[0]; lv.y = ll[1]; lv.z = ll[2]; lv.w = ll[3];
            *(ushort4*)&Ah[idx] = hv;
            *(ushort4*)&Al[idx] = lv;
        }
    }
    __syncthreads();

    const int dcol = lane & 15;
    const int d = wave * 16 + dcol;

    f32x4 acc[3][4];
    {
        const float b0 = bq[d], b1 = bk[d], b2 = bv[d];
        #pragma unroll
        for (int lt = 0; lt < 4; ++lt) {
            acc[0][lt] = (f32x4){b0, b0, b0, b0};
            acc[1][lt] = (f32x4){b1, b1, b1, b1};
            acc[2][lt] = (f32x4){b2, b2, b2, b2};
        }
    }

    #pragma unroll
    for (int ks = 0; ks < 4; ++ks) {
        bf16x8 bh[3], bl[3];
        if (ks == 0) {
            #pragma unroll
            for (int m = 0; m < 3; ++m) { bh[m] = bh0[m]; bl[m] = bl0[m]; }
        } else {
            #pragma unroll
            for (int m = 0; m < 3; ++m) {
                const int fi = ((m * 8 + wave) * 4 + ks) * 64 + lane;
                bh[m] = WhV[fi];
                bl[m] = WlV[fi];
            }
        }
        #pragma unroll
        for (int lt = 0; lt < 4; ++lt) {
            const bf16x8 ah = *(const bf16x8*)&Ah[((lt * 4 + ks) * 64 + lane) * 8];
            const bf16x8 al = *(const bf16x8*)&Al[((lt * 4 + ks) * 64 + lane) * 8];
            #pragma unroll
            for (int m = 0; m < 3; ++m) {
                acc[m][lt] = __builtin_amdgcn_mfma_f32_16x16x32_bf16(
                    ah, bh[m], acc[m][lt], 0, 0, 0);
                acc[m][lt] = __builtin_amdgcn_mfma_f32_16x16x32_bf16(
                    al, bh[m], acc[m][lt], 0, 0, 0);
                acc[m][lt] = __builtin_amdgcn_mfma_f32_16x16x32_bf16(
                    ah, bl[m], acc[m][lt], 0, 0, 0);
            }
        }
    }

    const int lrow0 = (lane >> 4) * 4;
    float psk = 0.f, pskv = 0.f;
    #pragma unroll
    for (int lt = 0; lt < 4; ++lt) {
        const f32x4 q4 = acc[0][lt];
        const f32x4 k4 = acc[1][lt];
        const f32x4 v4 = acc[2][lt];
        ushort eh[4], zh[4];
        #pragma unroll
        for (int r = 0; r < 4; ++r) {
            const int l = l0 + lt * 16 + lrow0 + r;
            const float e = __expf(k4[r]);
            const float z = e * v4[r];
            const float s = 1.f / (1.f + __expf(-q4[r]));
            sqh[((size_t)n * SL + l) * DM + d] = (ushort)(s * 65535.f + 0.5f);
            eh[r] = bf16_rne(e);
            zh[r] = bf16_rne(z);
            psk  += e;
            pskv += z;
        }
        // tiled store: tile jt = (l0+lt*16)/16, row d, jo = lrow0..lrow0+3
        const size_t tb = ((size_t)n * NTP + PADF + ((l0 + lt * 16) >> 4)) * 2048
                        + (size_t)d * 16 + lrow0;
        ushort4 ev; ev.x = eh[0]; ev.y = eh[1]; ev.z = eh[2]; ev.w = eh[3];
        ushort4 zv; zv.x = zh[0]; zv.y = zh[1]; zv.z = zh[2]; zv.w = zh[3];
        *(ushort4*)&ekTF [tb] = ev;
        *(ushort4*)&ekvTF[tb] = zv;
    }
    {
        float a = psk, b = pskv;
        a += __shfl_xor(a, 16, 64); a += __shfl_xor(a, 32, 64);
        b += __shfl_xor(b, 16, 64); b += __shfl_xor(b, 32, 64);
        if (lane < 16) {
            const size_t o = ((size_t)n * 32 + bx) * DM + d;
            Pk [o] = a;
            Pkv[o] = b;
        }
    }
}

// FUSED band correction + output projection, wave-local handoff.
// Starts by reducing the 32 Pk/Pkv segments into LDS (L2-hot, coalesced).
__global__ __launch_bounds__(256, 4) void band_out_kernel(
    const ushort* __restrict__ ekTF, const ushort* __restrict__ ekvTF,
    const ushort* __restrict__ WB,
    const float* __restrict__ Pk, const float* __restrict__ Pkv,
    const ushort* __restrict__ sqg,
    const ushort* __restrict__ Wh, const ushort* __restrict__ Wl,
    const float* __restrict__ bo, float* __restrict__ out)
{
    __shared__ __align__(16) union {
        float ylds[64 * YST];   // y fp32, [row l_local][col d]
        float ot[128 * 65];     // out transpose buffer [c][l_local]
    } u;
    __shared__ float SkL[DM], SkvL[DM];

    const int bid = blockIdx.x;          // 0..1023
    const int xcd = bid & 7;
    const int slot = bid >> 3;           // 0..127
    const int nsub = slot >> 5;          // 0..3
    const int itg  = slot & 31;          // 0..31
    const int n = xcd * 4 + nsub;        // 4 n's per XCD
    const int wave = threadIdx.x >> 6;
    const int lane = threadIdx.x & 63;
    const int it = itg * 4 + wave;       // 0..127
    const int i0 = it * 16;
    const int l0 = itg * 64;

    const int dcol = lane & 15;
    const int jgrp8 = (lane >> 4) << 3;

    // Hoist all 5 WB A-fragments (hides L2 latency under the Pk reduction).
    const bf16x8* WBv = (const bf16x8*)(WB + (size_t)it * 2560);
    bf16x8 aWB[5];
    #pragma unroll
    for (int ks = 0; ks < 5; ++ks) aWB[ks] = WBv[ks * 64 + lane];

    // ---- Reduce Pk/Pkv -> SkL/SkvL (threads 0-127: Sk, 128-255: Skv) ----
    {
        const int tdd = threadIdx.x & 127;
        const float* P = (threadIdx.x < 128) ? Pk : Pkv;
        float s = 0.f;
        #pragma unroll
        for (int seg = 0; seg < 32; ++seg)
            s += P[((size_t)n * 32 + seg) * DM + tdd];
        if (threadIdx.x < 128) SkL[tdd] = s; else SkvL[tdd] = s;
    }
    __syncthreads();

    // ---- Phase 1: banded MFMA over tiled layout ----
    f32x4 den[8], num[8];
    #pragma unroll
    for (int dt = 0; dt < 8; ++dt) {
        const float sk = SkL [dt * 16 + dcol];
        const float sv = SkvL[dt * 16 + dcol];
        den[dt] = (f32x4){sk, sk, sk, sk};
        num[dt] = (f32x4){sv, sv, sv, sv};
    }

    // lane-dependent tile select: jt_p = it + 2ks + (lane>>5); jo = ((lane>>4)&1)*8
    const size_t lsel = (size_t)(lane >> 5) * 2048 + (size_t)((lane >> 4) & 1) * 8
                      + (size_t)dcol * 16;
    #pragma unroll
    for (int ks = 0; ks < 5; ++ks) {
        const bf16x8 a = aWB[ks];
        const size_t tb = ((size_t)n * NTP + it + 2 * ks) * 2048 + lsel;
        #pragma unroll
        for (int dt = 0; dt < 8; ++dt) {
            const size_t rbase = tb + (size_t)dt * 256;   // dt*16 rows * 16 jo
            const bf16x8 bden = *(const bf16x8*)(ekTF  + rbase);
            const bf16x8 bnum = *(const bf16x8*)(ekvTF + rbase);
            den[dt] = __builtin_amdgcn_mfma_f32_16x16x32_bf16(a, bden, den[dt], 0, 0, 0);
            num[dt] = __builtin_amdgcn_mfma_f32_16x16x32_bf16(a, bnum, num[dt], 0, 0, 0);
        }
    }

    // Gate with sigmoid(q) (unorm16); write fp32 y into this wave's own LDS stripe.
    const int irow0 = (lane >> 4) << 2;
    #pragma unroll
    for (int dt = 0; dt < 8; ++dt) {
        const int d = dt * 16 + dcol;
        #pragma unroll
        for (int r = 0; r < 4; ++r) {
            const int i = i0 + irow0 + r;
            const float s = (float)sqg[((size_t)n * SL + i) * DM + d] * (1.f / 65535.f);
            const float y = s * num[dt][r] / den[dt][r];
            u.ylds[(wave * 16 + irow0 + r) * YST + d] = y;
        }
    }

    // ---- Handoff: read own stripe in A-octet order (wave-coherent) ----
    float af[4][8];
    {
        const int arow = wave * 16 + (lane & 15);
        #pragma unroll
        for (int ks = 0; ks < 4; ++ks) {
            const int base = arow * YST + ks * 32 + jgrp8;
            const float4 a0 = *(const float4*)&u.ylds[base];
            const float4 a1 = *(const float4*)&u.ylds[base + 4];
            af[ks][0] = a0.x; af[ks][1] = a0.y; af[ks][2] = a0.z; af[ks][3] = a0.w;
            af[ks][4] = a1.x; af[ks][5] = a1.y; af[ks][6] = a1.z; af[ks][7] = a1.w;
        }
    }
    __syncthreads();   // all waves done with ylds; ot may now overwrite

    bf16x8 yh[4], yl[4];
    #pragma unroll
    for (int ks = 0; ks < 4; ++ks) {
        #pragma unroll
        for (int t = 0; t < 8; ++t) {
            const float v = af[ks][t];
            const ushort h = bf16_rne(v);
            yh[ks][t] = (short)h;
            yl[ks][t] = (short)bf16_rne(v - bf16_to_f(h));
        }
    }

    // ---- Phase 2: out projection, own 16 rows x all 128 c ----
    f32x4 acc[8];
    #pragma unroll
    for (int ct = 0; ct < 8; ++ct) {
        const float b0 = bo[ct * 16 + dcol];
        acc[ct] = (f32x4){b0, b0, b0, b0};
    }

    const bf16x8* WhV = (const bf16x8*)Wh;
    const bf16x8* WlV = (const bf16x8*)Wl;
    #pragma unroll
    for (int ks = 0; ks < 4; ++ks) {
        #pragma unroll
        for (int ct = 0; ct < 8; ++ct) {
            const int fi = ((24 + ct) * 4 + ks) * 64 + lane;  // mat=3 (Wo)
            const bf16x8 bh = WhV[fi];
            const bf16x8 bl = WlV[fi];
            acc[ct] = __builtin_amdgcn_mfma_f32_16x16x32_bf16(yh[ks], bh, acc[ct], 0, 0, 0);
            acc[ct] = __builtin_amdgcn_mfma_f32_16x16x32_bf16(yl[ks], bh, acc[ct], 0, 0, 0);
            acc[ct] = __builtin_amdgcn_mfma_f32_16x16x32_bf16(yh[ks], bl, acc[ct], 0, 0, 0);
        }
    }

    // Transpose through LDS: ot[c][l_local]; C rows = wave's 16 l's.
    #pragma unroll
    for (int ct = 0; ct < 8; ++ct) {
        const int c = ct * 16 + dcol;
        #pragma unroll
        for (int r = 0; r < 4; ++r)
            u.ot[c * 65 + wave * 16 + irow0 + r] = acc[ct][r];
    }
    __syncthreads();

    // Coalesced store: 64 contiguous floats per c row.
    const int tid = threadIdx.x;
    #pragma unroll
    for (int rep = 0; rep < 32; ++rep) {
        const int e = rep * 256 + tid;
        const int c = e >> 6, l = e & 63;
        out[((size_t)n * DM + c) * SL + l0 + l] = u.ot[c * 65 + l];
    }
}

extern "C" void kernel_launch(void* const* d_in, const int* in_sizes, int n_in,
                              void* d_out, int out_size, void* d_ws, size_t ws_size,
                              hipStream_t stream)
{
    const float* x        = (const float*)d_in[0];
    const float* Wq       = (const float*)d_in[1];
    const float* bq       = (const float*)d_in[2];
    const float* Wk       = (const float*)d_in[3];
    const float* bk       = (const float*)d_in[4];
    const float* Wv       = (const float*)d_in[5];
    const float* bv       = (const float*)d_in[6];
    const float* Wo       = (const float*)d_in[7];
    const float* bo       = (const float*)d_in[8];
    const float* pos_bias = (const float*)d_in[9];
    float* out = (float*)d_out;

    const size_t NLD = (size_t)NB * SL * DM;
    ushort* sqh   = (ushort*)d_ws;
    ushort* ekTF  = sqh   + NLD;
    ushort* ekvTF = ekTF  + (size_t)NB * NTP * 2048;
    ushort* WB    = ekvTF + (size_t)NB * NTP * 2048;
    float*  Pk    = (float*)(WB + (size_t)128 * 2560);
    float*  Pkv   = Pk   + (size_t)NB * 32 * DM;
    ushort* Wh    = (ushort*)(Pkv + (size_t)NB * 32 * DM);
    ushort* Wl    = Wh + (size_t)4 * DM * DM;

    setup_kernel   <<<dim3(384),     512, 0, stream>>>(Wq, Wk, Wv, Wo, pos_bias,
                                                       Wh, Wl, WB);
    qkv_kernel     <<<dim3(32, NB),  512, 0, stream>>>(x, Wh, Wl, bq, bk, bv,
                                                       sqh, ekTF, ekvTF, Pk, Pkv);
    band_out_kernel<<<dim3(NB * 32), 256, 0, stream>>>(ekTF, ekvTF, WB, Pk, Pkv, sqh,
                                                       Wh, Wl, bo, out);
}

// Round 5
// 159.950 us; speedup vs baseline: 1.0133x; 1.0133x over previous
//
#include <hip/hip_runtime.h>
#include <math.h>

#define NB 32
#define DM 128
#define SL 2048
#define WIN 64
#define NT  (SL / 16)    // 128 j-tiles of 16
#define PADF 4           // front pad tiles (j in [-64,0))
#define PADB 6           // back pad tiles  (j in [SL, SL+96))
#define NTP (NT + PADF + PADB)   // 138 tiles per (n)
#define YST 132          // ylds row stride (floats)
#define NSEG 64          // qkv l-blocks per n (SL/32)

typedef __attribute__((ext_vector_type(8))) short bf16x8;
typedef __attribute__((ext_vector_type(8))) unsigned short u16x8;
typedef __attribute__((ext_vector_type(4))) float f32x4;

__device__ inline ushort bf16_rne(float f) {
    union { float f; unsigned u; } v; v.f = f;
    unsigned u = v.u;
    return (ushort)((u + 0x7FFFu + ((u >> 16) & 1u)) >> 16);
}
__device__ inline float bf16_to_f(ushort h) {
    union { unsigned u; float f; } v; v.u = ((unsigned)h) << 16;
    return v.f;
}
// hi = truncated top bits (1 op); lo = rne(residual) absorbs the trunc error.
__device__ inline ushort bf16_hi_trunc(float f) {
    union { float f; unsigned u; } v; v.f = f;
    return (ushort)(v.u >> 16);
}

// ---------------------------------------------------------------------------
// ws layout:
//   sqh   : NB*SL*DM ushort   sigmoid(q) as unorm16 (abs err <= 7.6e-6)
//   ekTF  : NB*NTP*2048 bf16  exp(k) in 16-j x 128-d tiles [n][jt][d][jo],
//                             jt offset by PADF; pad tiles zeroed by qkv bx<10
//   ekvTF : same              exp(k)*v
//   WB    : 128*2560 bf16     banded weights, A-frag order per 16-i tile
//   Pk/Pkv: NB*NSEG*DM fp32   per-block partial sums (reduced inside band_out)
//   Wh/Wl : 4*128*128 bf16    split W (Wq,Wk,Wv,Wo), B-frag order
// ---------------------------------------------------------------------------

// Setup: blocks 0..127 pack W (B-frag, split hi/lo); 128..383 build WB.
__global__ __launch_bounds__(512) void setup_kernel(
    const float* __restrict__ Wq, const float* __restrict__ Wk,
    const float* __restrict__ Wv, const float* __restrict__ Wo,
    const float* __restrict__ pos_bias,
    ushort* __restrict__ Wh, ushort* __restrict__ Wl,
    ushort* __restrict__ WB)
{
    const int b = blockIdx.x;
    const int tid = threadIdx.x;
    if (b < 128) {
        // ---- pack Wq/Wk/Wv/Wo into B-frag order, split hi/lo bf16 ----
        const int id = b;                 // (mat*8+ct)*4+ks
        const int mat = id >> 5;
        const int ct = (id & 31) >> 2, ks = id & 3;
        const int lane = tid >> 3, j = tid & 7;
        const int k = ks * 32 + (lane >> 4) * 8 + j;
        const int col = ct * 16 + (lane & 15);
        const float* W = (mat == 0) ? Wq : ((mat == 1) ? Wk : ((mat == 2) ? Wv : Wo));
        float w = W[k * DM + col];
        ushort h = bf16_rne(w);
        Wh[(size_t)id * 512 + tid] = h;
        Wl[(size_t)id * 512 + tid] = bf16_rne(w - bf16_to_f(h));
    } else {
        // ---- banded weights in A-frag order per 16-i tile, 2 blocks/tile ----
        const int idx = b - 128;          // 0..255
        const int it = idx >> 1;          // 0..127
        const int half = idx & 1;
        const int i0 = it * 16;
        const int tend = half * 1280 + 1280;
        for (int t = half * 1280 + tid; t < tend; t += 512) {
            const int ks = t >> 9;
            const int lane = (t >> 3) & 63;
            const int jj = t & 7;
            const int m = lane & 15;
            const int k = ks * 32 + ((lane >> 4) << 3) + jj;
            const int i = i0 + m;
            const int j = i0 - 64 + k;
            const int rel = k - 64 - m;  // j - i
            float val = 0.f;
            if (rel > -WIN && rel < WIN && j >= 0 && j < SL)
                val = __expf(pos_bias[(size_t)i * SL + j]) - 1.f;
            WB[(size_t)it * 2560 + t] = bf16_rne(val);
        }
    }
}

// QKV projection via split-bf16 MFMA.
// Block = (n, 32 l's), 512 threads / 8 waves; wave w owns dt slice w (16 d's)
// for all 3 matrices, 2 l-tiles. acc = 24 VGPR, LDS 16 KB -> 3 blocks/CU.
__global__ __launch_bounds__(512, 6) void qkv_kernel(
    const float* __restrict__ x,
    const ushort* __restrict__ Wh, const ushort* __restrict__ Wl,
    const float* __restrict__ bq, const float* __restrict__ bk,
    const float* __restrict__ bv,
    ushort* __restrict__ sqh, ushort* __restrict__ ekTF, ushort* __restrict__ ekvTF,
    float* __restrict__ Pk, float* __restrict__ Pkv)
{
    __shared__ ushort Ah[32 * 128];   // frag order: ((lt*4+ks)*64+lane)*8+j
    __shared__ ushort Al[32 * 128];
    const int n = blockIdx.y, bx = blockIdx.x, l0 = bx * 32;
    const int tid = threadIdx.x;
    const int wave = tid >> 6;        // = dt slice 0..7
    const int lane = tid & 63;

    // Pad-tile zeroing (front 4 + back 6 tiles per n), done by blocks bx<10.
    if (bx < 10) {
        const int jt_p = (bx < PADF) ? bx : (NT + bx);   // 0..3, 132..137
        const size_t zb = ((size_t)n * NTP + jt_p) * 2048 + (size_t)tid * 4;
        ushort4 z; z.x = 0; z.y = 0; z.z = 0; z.w = 0;
        *(ushort4*)&ekTF [zb] = z;
        *(ushort4*)&ekvTF[zb] = z;
    }

    // ---- stage x tile (32 l x 128 c) into A-frag order, split hi/lo ----
    {
        const int lo = tid & 31;          // l within tile
        const int cq = tid >> 5;          // 0..15, c0 = cq*8
        const int l  = l0 + lo;
        const int c0 = cq * 8;
        float xv[8];
        #pragma unroll
        for (int u = 0; u < 8; ++u)
            xv[u] = x[((size_t)n * DM + c0 + u) * SL + l];
        u16x8 hv, lv;
        #pragma unroll
        for (int u = 0; u < 8; ++u) {
            const ushort h = bf16_hi_trunc(xv[u]);
            hv[u] = h;
            lv[u] = bf16_rne(xv[u] - bf16_to_f(h));
        }
        const int lt = lo >> 4, m = lo & 15;
        const int ks = cq >> 2, oct = cq & 3;
        const int idx = ((lt * 4 + ks) * 64 + oct * 16 + m) * 8;
        *(u16x8*)&Ah[idx] = hv;
        *(u16x8*)&Al[idx] = lv;
    }
    __syncthreads();

    const int dcol = lane & 15;
    const int d = wave * 16 + dcol;

    f32x4 acc[3][2];
    {
        const float b0 = bq[d], b1 = bk[d], b2 = bv[d];
        #pragma unroll
        for (int lt = 0; lt < 2; ++lt) {
            acc[0][lt] = (f32x4){b0, b0, b0, b0};
            acc[1][lt] = (f32x4){b1, b1, b1, b1};
            acc[2][lt] = (f32x4){b2, b2, b2, b2};
        }
    }

    const bf16x8* WhV = (const bf16x8*)Wh;
    const bf16x8* WlV = (const bf16x8*)Wl;
    #pragma unroll
    for (int ks = 0; ks < 4; ++ks) {
        bf16x8 bh[3], bl[3];
        #pragma unroll
        for (int m = 0; m < 3; ++m) {
            const int fi = ((m * 8 + wave) * 4 + ks) * 64 + lane;
            bh[m] = WhV[fi];
            bl[m] = WlV[fi];
        }
        #pragma unroll
        for (int lt = 0; lt < 2; ++lt) {
            const bf16x8 ah = *(const bf16x8*)&Ah[((lt * 4 + ks) * 64 + lane) * 8];
            const bf16x8 al = *(const bf16x8*)&Al[((lt * 4 + ks) * 64 + lane) * 8];
            #pragma unroll
            for (int m = 0; m < 3; ++m) {
                acc[m][lt] = __builtin_amdgcn_mfma_f32_16x16x32_bf16(
                    ah, bh[m], acc[m][lt], 0, 0, 0);
                acc[m][lt] = __builtin_amdgcn_mfma_f32_16x16x32_bf16(
                    al, bh[m], acc[m][lt], 0, 0, 0);
                acc[m][lt] = __builtin_amdgcn_mfma_f32_16x16x32_bf16(
                    ah, bl[m], acc[m][lt], 0, 0, 0);
            }
        }
    }

    const int lrow0 = (lane >> 4) * 4;
    float psk = 0.f, pskv = 0.f;
    #pragma unroll
    for (int lt = 0; lt < 2; ++lt) {
        const f32x4 q4 = acc[0][lt];
        const f32x4 k4 = acc[1][lt];
        const f32x4 v4 = acc[2][lt];
        ushort eh[4], zh[4];
        #pragma unroll
        for (int r = 0; r < 4; ++r) {
            const int l = l0 + lt * 16 + lrow0 + r;
            const float e = __expf(k4[r]);
            const float z = e * v4[r];
            const float s = fminf(__builtin_amdgcn_rcpf(1.f + __expf(-q4[r])), 1.f);
            sqh[((size_t)n * SL + l) * DM + d] = (ushort)(s * 65535.f + 0.5f);
            eh[r] = bf16_rne(e);
            zh[r] = bf16_rne(z);
            psk  += e;
            pskv += z;
        }
        // tiled store: tile jt = bx*2 + lt, row d, jo = lrow0..lrow0+3
        const size_t tb = ((size_t)n * NTP + PADF + (bx * 2 + lt)) * 2048
                        + (size_t)d * 16 + lrow0;
        ushort4 ev; ev.x = eh[0]; ev.y = eh[1]; ev.z = eh[2]; ev.w = eh[3];
        ushort4 zv; zv.x = zh[0]; zv.y = zh[1]; zv.z = zh[2]; zv.w = zh[3];
        *(ushort4*)&ekTF [tb] = ev;
        *(ushort4*)&ekvTF[tb] = zv;
    }
    {
        float a = psk, b = pskv;
        a += __shfl_xor(a, 16, 64); a += __shfl_xor(a, 32, 64);
        b += __shfl_xor(b, 16, 64); b += __shfl_xor(b, 32, 64);
        if (lane < 16) {
            const size_t o = ((size_t)n * NSEG + bx) * DM + d;
            Pk [o] = a;
            Pkv[o] = b;
        }
    }
}

// FUSED band correction + output projection, wave-local handoff.
// Starts by reducing the NSEG Pk/Pkv segments into LDS (L2-hot, coalesced).
__global__ __launch_bounds__(256, 4) void band_out_kernel(
    const ushort* __restrict__ ekTF, const ushort* __restrict__ ekvTF,
    const ushort* __restrict__ WB,
    const float* __restrict__ Pk, const float* __restrict__ Pkv,
    const ushort* __restrict__ sqg,
    const ushort* __restrict__ Wh, const ushort* __restrict__ Wl,
    const float* __restrict__ bo, float* __restrict__ out)
{
    __shared__ __align__(16) union {
        float ylds[64 * YST];   // y fp32, [row l_local][col d]
        float ot[128 * 65];     // out transpose buffer [c][l_local]
    } u;
    __shared__ float SkL[DM], SkvL[DM];

    const int bid = blockIdx.x;          // 0..1023
    const int xcd = bid & 7;
    const int slot = bid >> 3;           // 0..127
    const int nsub = slot >> 5;          // 0..3
    const int itg  = slot & 31;          // 0..31
    const int n = xcd * 4 + nsub;        // 4 n's per XCD
    const int wave = threadIdx.x >> 6;
    const int lane = threadIdx.x & 63;
    const int it = itg * 4 + wave;       // 0..127
    const int i0 = it * 16;
    const int l0 = itg * 64;

    const int dcol = lane & 15;
    const int jgrp8 = (lane >> 4) << 3;

    // Hoist all 5 WB A-fragments (hides L2 latency under the Pk reduction).
    const bf16x8* WBv = (const bf16x8*)(WB + (size_t)it * 2560);
    bf16x8 aWB[5];
    #pragma unroll
    for (int ks = 0; ks < 5; ++ks) aWB[ks] = WBv[ks * 64 + lane];

    // ---- Reduce Pk/Pkv -> SkL/SkvL (threads 0-127: Sk, 128-255: Skv) ----
    {
        const int tdd = threadIdx.x & 127;
        const float* P = (threadIdx.x < 128) ? Pk : Pkv;
        float s = 0.f;
        #pragma unroll
        for (int seg = 0; seg < NSEG; ++seg)
            s += P[((size_t)n * NSEG + seg) * DM + tdd];
        if (threadIdx.x < 128) SkL[tdd] = s; else SkvL[tdd] = s;
    }
    __syncthreads();

    // ---- Phase 1: banded MFMA over tiled layout ----
    f32x4 den[8], num[8];
    #pragma unroll
    for (int dt = 0; dt < 8; ++dt) {
        const float sk = SkL [dt * 16 + dcol];
        const float sv = SkvL[dt * 16 + dcol];
        den[dt] = (f32x4){sk, sk, sk, sk};
        num[dt] = (f32x4){sv, sv, sv, sv};
    }

    // lane-dependent tile select: jt_p = it + 2ks + (lane>>5); jo = ((lane>>4)&1)*8
    const size_t lsel = (size_t)(lane >> 5) * 2048 + (size_t)((lane >> 4) & 1) * 8
                      + (size_t)dcol * 16;
    #pragma unroll
    for (int ks = 0; ks < 5; ++ks) {
        const bf16x8 a = aWB[ks];
        const size_t tb = ((size_t)n * NTP + it + 2 * ks) * 2048 + lsel;
        #pragma unroll
        for (int dt = 0; dt < 8; ++dt) {
            const size_t rbase = tb + (size_t)dt * 256;   // dt*16 rows * 16 jo
            const bf16x8 bden = *(const bf16x8*)(ekTF  + rbase);
            const bf16x8 bnum = *(const bf16x8*)(ekvTF + rbase);
            den[dt] = __builtin_amdgcn_mfma_f32_16x16x32_bf16(a, bden, den[dt], 0, 0, 0);
            num[dt] = __builtin_amdgcn_mfma_f32_16x16x32_bf16(a, bnum, num[dt], 0, 0, 0);
        }
    }

    // Gate with sigmoid(q) (unorm16); write fp32 y into this wave's own LDS stripe.
    const int irow0 = (lane >> 4) << 2;
    #pragma unroll
    for (int dt = 0; dt < 8; ++dt) {
        const int d = dt * 16 + dcol;
        #pragma unroll
        for (int r = 0; r < 4; ++r) {
            const int i = i0 + irow0 + r;
            const float s = (float)sqg[((size_t)n * SL + i) * DM + d] * (1.f / 65535.f);
            const float y = s * num[dt][r] * __builtin_amdgcn_rcpf(den[dt][r]);
            u.ylds[(wave * 16 + irow0 + r) * YST + d] = y;
        }
    }

    // ---- Handoff: read own stripe in A-octet order, convert immediately ----
    bf16x8 yh[4], yl[4];
    {
        const int arow = wave * 16 + (lane & 15);
        #pragma unroll
        for (int ks = 0; ks < 4; ++ks) {
            const int base = arow * YST + ks * 32 + jgrp8;
            const float4 a0 = *(const float4*)&u.ylds[base];
            const float4 a1 = *(const float4*)&u.ylds[base + 4];
            float af[8];
            af[0] = a0.x; af[1] = a0.y; af[2] = a0.z; af[3] = a0.w;
            af[4] = a1.x; af[5] = a1.y; af[6] = a1.z; af[7] = a1.w;
            #pragma unroll
            for (int t = 0; t < 8; ++t) {
                const ushort h = bf16_hi_trunc(af[t]);
                yh[ks][t] = (short)h;
                yl[ks][t] = (short)bf16_rne(af[t] - bf16_to_f(h));
            }
        }
    }
    __syncthreads();   // all waves done with ylds; ot may now overwrite

    // ---- Phase 2: out projection, own 16 rows x all 128 c ----
    f32x4 acc[8];
    #pragma unroll
    for (int ct = 0; ct < 8; ++ct) {
        const float b0 = bo[ct * 16 + dcol];
        acc[ct] = (f32x4){b0, b0, b0, b0};
    }

    const bf16x8* WhV = (const bf16x8*)Wh;
    const bf16x8* WlV = (const bf16x8*)Wl;
    #pragma unroll
    for (int ks = 0; ks < 4; ++ks) {
        #pragma unroll
        for (int ct = 0; ct < 8; ++ct) {
            const int fi = ((24 + ct) * 4 + ks) * 64 + lane;  // mat=3 (Wo)
            const bf16x8 bh = WhV[fi];
            const bf16x8 bl = WlV[fi];
            acc[ct] = __builtin_amdgcn_mfma_f32_16x16x32_bf16(yh[ks], bh, acc[ct], 0, 0, 0);
            acc[ct] = __builtin_amdgcn_mfma_f32_16x16x32_bf16(yl[ks], bh, acc[ct], 0, 0, 0);
            acc[ct] = __builtin_amdgcn_mfma_f32_16x16x32_bf16(yh[ks], bl, acc[ct], 0, 0, 0);
        }
    }

    // Transpose through LDS: ot[c][l_local]; C rows = wave's 16 l's.
    #pragma unroll
    for (int ct = 0; ct < 8; ++ct) {
        const int c = ct * 16 + dcol;
        #pragma unroll
        for (int r = 0; r < 4; ++r)
            u.ot[c * 65 + wave * 16 + irow0 + r] = acc[ct][r];
    }
    __syncthreads();

    // Coalesced store: 64 contiguous floats per c row.
    const int tid = threadIdx.x;
    #pragma unroll
    for (int rep = 0; rep < 32; ++rep) {
        const int e = rep * 256 + tid;
        const int c = e >> 6, l = e & 63;
        out[((size_t)n * DM + c) * SL + l0 + l] = u.ot[c * 65 + l];
    }
}

extern "C" void kernel_launch(void* const* d_in, const int* in_sizes, int n_in,
                              void* d_out, int out_size, void* d_ws, size_t ws_size,
                              hipStream_t stream)
{
    const float* x        = (const float*)d_in[0];
    const float* Wq       = (const float*)d_in[1];
    const float* bq       = (const float*)d_in[2];
    const float* Wk       = (const float*)d_in[3];
    const float* bk       = (const float*)d_in[4];
    const float* Wv       = (const float*)d_in[5];
    const float* bv       = (const float*)d_in[6];
    const float* Wo       = (const float*)d_in[7];
    const float* bo       = (const float*)d_in[8];
    const float* pos_bias = (const float*)d_in[9];
    float* out = (float*)d_out;

    const size_t NLD = (size_t)NB * SL * DM;
    ushort* sqh   = (ushort*)d_ws;
    ushort* ekTF  = sqh   + NLD;
    ushort* ekvTF = ekTF  + (size_t)NB * NTP * 2048;
    ushort* WB    = ekvTF + (size_t)NB * NTP * 2048;
    float*  Pk    = (float*)(WB + (size_t)128 * 2560);
    float*  Pkv   = Pk   + (size_t)NB * NSEG * DM;
    ushort* Wh    = (ushort*)(Pkv + (size_t)NB * NSEG * DM);
    ushort* Wl    = Wh + (size_t)4 * DM * DM;

    setup_kernel   <<<dim3(384),      512, 0, stream>>>(Wq, Wk, Wv, Wo, pos_bias,
                                                        Wh, Wl, WB);
    qkv_kernel     <<<dim3(NSEG, NB), 512, 0, stream>>>(x, Wh, Wl, bq, bk, bv,
                                                        sqh, ekTF, ekvTF, Pk, Pkv);
    band_out_kernel<<<dim3(NB * 32),  256, 0, stream>>>(ekTF, ekvTF, WB, Pk, Pkv, sqh,
                                                        Wh, Wl, bo, out);
}